// Round 1
// baseline (401.868 us; speedup 1.0000x reference)
//
#include <hip/hip_runtime.h>

// SoftFullAttention — restructured:
//   vertical[b,c,h,w]   = sum_c' src[c',h,w] Fv[b,w][c',c] + P_v[h,w]*s1v[b,w][c] + t1v[b,w][c]
//   horizontal[b,c,h,w] = sum_c' src[c',h,w] Fh[b,h][c',c] + P_h[w,h]*s1h[b,h][c] + t1h[b,h][c]
// where Fv/s1/t1 derive from the 32x32 Gram matrix of target columns/rows.
// All fp32. out channels: [0:32) horizontal, [32:64) vertical.

#define OFF_GH   0
#define OFF_GV   1048576
#define OFF_QH   2097152
#define OFF_TSH  2129920
#define OFF_QV   2162688
#define OFF_TSV  2195456
#define OFF_PH   2228224
#define OFF_PV   2229504

// ---------------- prep: per-branch folded constants (1280 floats) ----------------
// layout: [0:1024) Wc = w1^T w2 ; [1024) a ; [1056) d ; [1088) u ; [1120) v ; [1152) alpha,beta,gamma,delta
__global__ __launch_bounds__(256) void prep_kernel(
    const float* __restrict__ w1, const float* __restrict__ b1,
    const float* __restrict__ w2, const float* __restrict__ b2,
    float* __restrict__ outp)
{
  __shared__ float lw1[1024], lw2[1024], lb1[32], lb2[32], lr1[32], lr2[32];
  const int t = threadIdx.x;
  for (int k = 0; k < 4; ++k) { lw1[t + 256*k] = w1[t + 256*k]; lw2[t + 256*k] = w2[t + 256*k]; }
  if (t < 32) { lb1[t] = b1[t]; lb2[t] = b2[t]; }
  __syncthreads();
  if (t < 32)      { float s = 0; for (int c = 0; c < 32; ++c) s += lw1[t*32 + c];      lr1[t] = s; }
  else if (t < 64) { int i = t - 32; float s = 0; for (int c = 0; c < 32; ++c) s += lw2[i*32 + c]; lr2[i] = s; }
  __syncthreads();
  for (int k = 0; k < 4; ++k) {
    const int e = t + 256*k, cp = e >> 5, cq = e & 31;
    float s = 0;
    for (int c1 = 0; c1 < 32; ++c1) s += lw1[c1*32 + cp] * lw2[c1*32 + cq];
    outp[e] = s;
  }
  if (t < 32)       { float s = 0; for (int c1 = 0; c1 < 32; ++c1) s += lw1[c1*32 + t]*lr2[c1];        outp[1024 + t] = s; }
  else if (t < 64)  { int i = t-32; float s = 0; for (int c1 = 0; c1 < 32; ++c1) s += lw1[c1*32+i]*lb2[c1]; outp[1056 + i] = s; }
  else if (t < 96)  { int i = t-64; float s = 0; for (int c1 = 0; c1 < 32; ++c1) s += lr1[c1]*lw2[c1*32+i]; outp[1088 + i] = s; }
  else if (t < 128) { int i = t-96; float s = 0; for (int c1 = 0; c1 < 32; ++c1) s += lb1[c1]*lw2[c1*32+i]; outp[1120 + i] = s; }
  else if (t == 128){ float s = 0; for (int i = 0; i < 32; ++i) s += lr1[i]*lr2[i]; outp[1152] = s; }
  else if (t == 129){ float s = 0; for (int i = 0; i < 32; ++i) s += lr1[i]*lb2[i]; outp[1153] = s; }
  else if (t == 130){ float s = 0; for (int i = 0; i < 32; ++i) s += lb1[i]*lr2[i]; outp[1154] = s; }
  else if (t == 131){ float s = 0; for (int i = 0; i < 32; ++i) s += lb1[i]*lb2[i]; outp[1155] = s; }
}

// ---------------- Gram: per (b,x) 32x32 target Gram + q + ts ----------------
// VERT: x = w (columns, k runs over g/H). HORIZ: x = h (rows, k runs over v/W).
// grid 256 blocks (XCD-swizzled), 4 waves/block, wave = one x. 16 accums/lane.
template<bool VERT>
__global__ __launch_bounds__(256) void gram_kernel(
    const float* __restrict__ T, const float* __restrict__ P,
    float* __restrict__ Gws, float* __restrict__ qws, float* __restrict__ tsws)
{
  __shared__ float tile[4*2180];   // [x-wave][32 c][64 k + 4 pad]
  __shared__ float ptile[4*68];
  const int blk = blockIdx.x;
  const int node = blk & 7, slot = blk >> 3;
  const int b = slot & 3;
  const int q4 = node*8 + (slot >> 2);   // 0..63  (x-quad)
  const int x0 = q4 * 4;
  const int t = threadIdx.x;
  const int wave = t >> 6, lane = t & 63;
  const int c1g = lane & 7, c2g = lane >> 3;

  float acc[4][4] = {};
  float qa[4] = {}, tsa[4] = {};

  for (int ch = 0; ch < 4; ++ch) {
    const int k0 = ch * 64;
    __syncthreads();
    if (VERT) {
      const int gs = t & 63, cq = t >> 6;
      #pragma unroll
      for (int k = 0; k < 8; ++k) {
        const int c = cq*8 + k;
        const float4 v = *(const float4*)&T[(((b*32 + c)*256) + (k0 + gs))*256 + x0];
        tile[0*2180 + c*68 + gs] = v.x;
        tile[1*2180 + c*68 + gs] = v.y;
        tile[2*2180 + c*68 + gs] = v.z;
        tile[3*2180 + c*68 + gs] = v.w;
      }
      if (t < 64) {
        const float4 v = *(const float4*)&P[(k0 + t)*256 + x0];  // P_v[g][w]
        ptile[0*68 + t] = v.x; ptile[1*68 + t] = v.y; ptile[2*68 + t] = v.z; ptile[3*68 + t] = v.w;
      }
    } else {
      const int vq = t & 15, hh = (t >> 4) & 3, cq = t >> 6;
      #pragma unroll
      for (int k = 0; k < 8; ++k) {
        const int c = cq*8 + k;
        const float4 v = *(const float4*)&T[(((b*32 + c)*256) + (x0 + hh))*256 + k0 + vq*4];
        *(float4*)&tile[hh*2180 + c*68 + vq*4] = v;
      }
      if (t < 64) {
        #pragma unroll
        for (int hh2 = 0; hh2 < 4; ++hh2)
          ptile[hh2*68 + t] = P[(k0 + t)*256 + x0 + hh2];        // P_h[v][h]
      }
    }
    __syncthreads();
    const float* tw = &tile[wave*2180];
    #pragma unroll
    for (int g4 = 0; g4 < 16; ++g4) {
      float4 av[4], bv[4];
      #pragma unroll
      for (int i = 0; i < 4; ++i) av[i] = *(const float4*)&tw[(4*c1g + i)*68 + g4*4];
      #pragma unroll
      for (int j = 0; j < 4; ++j) bv[j] = *(const float4*)&tw[(4*c2g + j)*68 + g4*4];
      #pragma unroll
      for (int i = 0; i < 4; ++i)
        #pragma unroll
        for (int j = 0; j < 4; ++j) {
          acc[i][j] += av[i].x*bv[j].x; acc[i][j] += av[i].y*bv[j].y;
          acc[i][j] += av[i].z*bv[j].z; acc[i][j] += av[i].w*bv[j].w;
        }
    }
    if (c1g == 0) {   // q / ts by 8 lanes (c2g covers all c)
      #pragma unroll
      for (int g4 = 0; g4 < 16; ++g4) {
        const float4 p4 = *(const float4*)&ptile[wave*68 + g4*4];
        #pragma unroll
        for (int j = 0; j < 4; ++j) {
          const float4 bv = *(const float4*)&tw[(4*c2g + j)*68 + g4*4];
          qa[j]  += p4.x*bv.x + p4.y*bv.y + p4.z*bv.z + p4.w*bv.w;
          tsa[j] += bv.x + bv.y + bv.z + bv.w;
        }
      }
    }
  }
  // G store: per-wave LDS transpose -> coalesced float4 stores
  __syncthreads();
  float* gw = &tile[wave*2180];
  #pragma unroll
  for (int i = 0; i < 4; ++i)
    #pragma unroll
    for (int j = 0; j < 4; ++j)
      gw[(4*c1g + i)*36 + (4*c2g + j)] = acc[i][j];
  __syncthreads();
  const int x = x0 + wave;
  const int gbase = (((b << 8) + x)) * 1024;
  #pragma unroll
  for (int k = 0; k < 4; ++k) {
    const int id = lane + 64*k;
    const int row = id >> 3, col4 = id & 7;
    const float4 v = *(const float4*)&gw[row*36 + col4*4];
    *(float4*)&Gws[gbase + row*32 + col4*4] = v;
  }
  if (c1g == 0) {
    #pragma unroll
    for (int j = 0; j < 4; ++j) {
      qws[((b << 8) + x)*32 + 4*c2g + j]  = qa[j];
      tsws[((b << 8) + x)*32 + 4*c2g + j] = tsa[j];
    }
  }
}

// ---------------- fold: G,q,ts -> F (in place over G), s1,t1 (over q,ts) ----------------
__global__ __launch_bounds__(256) void fold_kernel(float* __restrict__ ws)
{
  const int wgid = blockIdx.x*4 + (threadIdx.x >> 6);  // 0..2047
  const int lane = threadIdx.x & 63;
  const int n = lane & 31, mg = lane >> 5;
  const bool horiz = (wgid < 1024);
  const int idx = wgid & 1023;
  float* G   = ws + (horiz ? OFF_GH  : OFF_GV)  + idx*1024;
  float* q   = ws + (horiz ? OFF_QH  : OFF_QV)  + idx*32;
  float* tsp = ws + (horiz ? OFF_TSH : OFF_TSV) + idx*32;
  const float* pp = ws + (horiz ? OFF_PH : OFF_PV);
  float facc[16] = {};
  float s1a = 0.f, t1a = 0.f;
  #pragma unroll
  for (int k4 = 0; k4 < 8; ++k4) {
    float g[4];
    #pragma unroll
    for (int e = 0; e < 4; ++e) g[e] = G[(k4*4 + e)*32 + n];
    const float4 u4 = *(const float4*)&pp[1088 + k4*4];
    const float4 v4 = *(const float4*)&pp[1120 + k4*4];
    s1a += u4.x*g[0] + u4.y*g[1] + u4.z*g[2] + u4.w*g[3];
    t1a += v4.x*g[0] + v4.y*g[1] + v4.z*g[2] + v4.w*g[3];
    #pragma unroll
    for (int i = 0; i < 16; ++i) {
      const float4 wc = *(const float4*)&pp[(mg*16 + i)*32 + k4*4];
      facc[i] += wc.x*g[0] + wc.y*g[1] + wc.z*g[2] + wc.w*g[3];
    }
  }
  const float qv = q[n], tv = tsp[n];
  const float al = pp[1152], be = pp[1153], ga = pp[1154], de = pp[1155];
  #pragma unroll
  for (int i = 0; i < 16; ++i) {
    const int m = mg*16 + i;
    G[m*32 + n] = facc[i] + pp[1024 + m]*qv + pp[1056 + m]*tv;   // F[m][n]
  }
  if (mg == 0) {
    q[n]   = s1a + al*qv + be*tv;   // s1
    tsp[n] = t1a + ga*qv + de*tv;   // t1
  }
}

// ---------------- vertical output ----------------
// grid 512 (XCD-swizzled (b, h-half, w-quad)), wave = one w. F column pair in regs.
__global__ __launch_bounds__(256) void outv_kernel(
    const float* __restrict__ S, const float* __restrict__ Pv,
    const float* __restrict__ Fws, const float* __restrict__ s1ws, const float* __restrict__ t1ws,
    float* __restrict__ out)
{
  __shared__ float tile[4*1156];    // [w][32 c'][32 h + 4]
  __shared__ float ptile[4*36];
  __shared__ float oLDS[32*161];    // [c][h*5 + w]
  const int blk = blockIdx.x;
  const int node = blk & 7, slot = blk >> 3;
  const int b = slot & 3;
  const int hhalf = (slot >> 2) & 1;
  const int wq = node*8 + (slot >> 3);
  const int x0 = wq*4;
  const int t = threadIdx.x;
  const int wave = t >> 6, lane = t & 63;
  const int cg = lane & 15, hg = lane >> 4;
  const int w = x0 + wave;
  const int base = (b << 8) + w;
  float f[2][32];
  #pragma unroll
  for (int p = 0; p < 2; ++p)
    #pragma unroll
    for (int c = 0; c < 32; ++c)
      f[p][c] = Fws[base*1024 + c*32 + 2*cg + p];
  float s1r[2], t1r[2];
  #pragma unroll
  for (int p = 0; p < 2; ++p) { s1r[p] = s1ws[base*32 + 2*cg + p]; t1r[p] = t1ws[base*32 + 2*cg + p]; }

  for (int hc = 0; hc < 4; ++hc) {
    const int h0 = (hhalf*4 + hc) * 32;
    __syncthreads();
    {
      const int hs = t & 31, cq = t >> 5;
      #pragma unroll
      for (int k = 0; k < 4; ++k) {
        const int c = cq*4 + k;
        const float4 v = *(const float4*)&S[(((b*32 + c)*256) + (h0 + hs))*256 + x0];
        tile[0*1156 + c*36 + hs] = v.x;
        tile[1*1156 + c*36 + hs] = v.y;
        tile[2*1156 + c*36 + hs] = v.z;
        tile[3*1156 + c*36 + hs] = v.w;
      }
      if (t < 32) {
        const float4 v = *(const float4*)&Pv[(h0 + t)*256 + x0];
        ptile[0*36 + t] = v.x; ptile[1*36 + t] = v.y; ptile[2*36 + t] = v.z; ptile[3*36 + t] = v.w;
      }
    }
    __syncthreads();
    float acc[2][8] = {};
    const float* tw = &tile[wave*1156];
    #pragma unroll
    for (int c = 0; c < 32; ++c) {
      const float4 lo = *(const float4*)&tw[c*36 + hg*8];
      const float4 hi = *(const float4*)&tw[c*36 + hg*8 + 4];
      #pragma unroll
      for (int p = 0; p < 2; ++p) {
        acc[p][0] += f[p][c]*lo.x; acc[p][1] += f[p][c]*lo.y;
        acc[p][2] += f[p][c]*lo.z; acc[p][3] += f[p][c]*lo.w;
        acc[p][4] += f[p][c]*hi.x; acc[p][5] += f[p][c]*hi.y;
        acc[p][6] += f[p][c]*hi.z; acc[p][7] += f[p][c]*hi.w;
      }
    }
    #pragma unroll
    for (int p = 0; p < 2; ++p)
      #pragma unroll
      for (int e = 0; e < 8; ++e) {
        const int h32 = hg*8 + e;
        const float pv = ptile[wave*36 + h32];
        oLDS[(2*cg + p)*161 + h32*5 + wave] = acc[p][e] + pv*s1r[p] + t1r[p];
      }
    __syncthreads();
    #pragma unroll
    for (int k = 0; k < 4; ++k) {
      const int id = t + 256*k;
      const int c = id >> 5, hh = id & 31;
      float4 o;
      o.x = oLDS[c*161 + hh*5 + 0];
      o.y = oLDS[c*161 + hh*5 + 1];
      o.z = oLDS[c*161 + hh*5 + 2];
      o.w = oLDS[c*161 + hh*5 + 3];
      *(float4*)&out[(((b*64 + 32 + c)*256) + (h0 + hh))*256 + x0] = o;
    }
  }
}

// ---------------- horizontal output ----------------
// grid 512 (b, h-quad, w-half), wave = one h; everything w-contiguous.
__global__ __launch_bounds__(256) void outh_kernel(
    const float* __restrict__ S, const float* __restrict__ Ph,
    const float* __restrict__ Fws, const float* __restrict__ s1ws, const float* __restrict__ t1ws,
    float* __restrict__ out)
{
  __shared__ float tile[4*1156];    // [h][32 c'][32 w + 4]
  __shared__ float ptile[4*36];
  const int blk = blockIdx.x;
  const int b = blk & 3;
  const int hq = (blk >> 2) & 63;
  const int whalf = blk >> 8;
  const int h0 = hq*4;
  const int t = threadIdx.x;
  const int wave = t >> 6, lane = t & 63;
  const int cg = lane & 15, wg = lane >> 4;
  const int h = h0 + wave;
  const int base = (b << 8) + h;
  float f[2][32];
  #pragma unroll
  for (int p = 0; p < 2; ++p)
    #pragma unroll
    for (int c = 0; c < 32; ++c)
      f[p][c] = Fws[base*1024 + c*32 + 2*cg + p];
  float s1r[2], t1r[2];
  #pragma unroll
  for (int p = 0; p < 2; ++p) { s1r[p] = s1ws[base*32 + 2*cg + p]; t1r[p] = t1ws[base*32 + 2*cg + p]; }

  for (int wc = 0; wc < 4; ++wc) {
    const int w0 = (whalf*4 + wc) * 32;
    __syncthreads();
    {
      const int wq8 = t & 7, hh = (t >> 3) & 3, cq = t >> 5;
      #pragma unroll
      for (int k = 0; k < 4; ++k) {
        const int c = cq*4 + k;
        const float4 v = *(const float4*)&S[(((b*32 + c)*256) + (h0 + hh))*256 + w0 + wq8*4];
        *(float4*)&tile[hh*1156 + c*36 + wq8*4] = v;
      }
      if (t < 32) {
        #pragma unroll
        for (int hh2 = 0; hh2 < 4; ++hh2)
          ptile[hh2*36 + t] = Ph[(w0 + t)*256 + h0 + hh2];   // P_h[w][h]
      }
    }
    __syncthreads();
    float acc[2][8] = {};
    const float* tw = &tile[wave*1156];
    #pragma unroll
    for (int c = 0; c < 32; ++c) {
      const float4 lo = *(const float4*)&tw[c*36 + wg*8];
      const float4 hi = *(const float4*)&tw[c*36 + wg*8 + 4];
      #pragma unroll
      for (int p = 0; p < 2; ++p) {
        acc[p][0] += f[p][c]*lo.x; acc[p][1] += f[p][c]*lo.y;
        acc[p][2] += f[p][c]*lo.z; acc[p][3] += f[p][c]*lo.w;
        acc[p][4] += f[p][c]*hi.x; acc[p][5] += f[p][c]*hi.y;
        acc[p][6] += f[p][c]*hi.z; acc[p][7] += f[p][c]*hi.w;
      }
    }
    #pragma unroll
    for (int p = 0; p < 2; ++p) {
      float4 o1, o2;
      o1.x = acc[p][0] + ptile[wave*36 + wg*8 + 0]*s1r[p] + t1r[p];
      o1.y = acc[p][1] + ptile[wave*36 + wg*8 + 1]*s1r[p] + t1r[p];
      o1.z = acc[p][2] + ptile[wave*36 + wg*8 + 2]*s1r[p] + t1r[p];
      o1.w = acc[p][3] + ptile[wave*36 + wg*8 + 3]*s1r[p] + t1r[p];
      o2.x = acc[p][4] + ptile[wave*36 + wg*8 + 4]*s1r[p] + t1r[p];
      o2.y = acc[p][5] + ptile[wave*36 + wg*8 + 5]*s1r[p] + t1r[p];
      o2.z = acc[p][6] + ptile[wave*36 + wg*8 + 6]*s1r[p] + t1r[p];
      o2.w = acc[p][7] + ptile[wave*36 + wg*8 + 7]*s1r[p] + t1r[p];
      const int ob = (((b*64 + 2*cg + p)*256) + h)*256 + w0 + wg*8;
      *(float4*)&out[ob]     = o1;
      *(float4*)&out[ob + 4] = o2;
    }
  }
}

extern "C" void kernel_launch(void* const* d_in, const int* in_sizes, int n_in,
                              void* d_out, int out_size, void* d_ws, size_t ws_size,
                              hipStream_t stream) {
  const float* src = (const float*)d_in[0];
  const float* tgt = (const float*)d_in[1];
  const float* Pv  = (const float*)d_in[2];
  const float* Ph  = (const float*)d_in[3];
  const float* w1v = (const float*)d_in[4];
  const float* b1v = (const float*)d_in[5];
  const float* w2v = (const float*)d_in[6];
  const float* b2v = (const float*)d_in[7];
  const float* w1h = (const float*)d_in[8];
  const float* b1h = (const float*)d_in[9];
  const float* w2h = (const float*)d_in[10];
  const float* b2h = (const float*)d_in[11];
  float* ws  = (float*)d_ws;
  float* out = (float*)d_out;

  prep_kernel<<<1, 256, 0, stream>>>(w1h, b1h, w2h, b2h, ws + OFF_PH);
  prep_kernel<<<1, 256, 0, stream>>>(w1v, b1v, w2v, b2v, ws + OFF_PV);
  gram_kernel<true ><<<256, 256, 0, stream>>>(tgt, Pv, ws + OFF_GV, ws + OFF_QV, ws + OFF_TSV);
  gram_kernel<false><<<256, 256, 0, stream>>>(tgt, Ph, ws + OFF_GH, ws + OFF_QH, ws + OFF_TSH);
  fold_kernel<<<512, 256, 0, stream>>>(ws);
  outv_kernel<<<512, 256, 0, stream>>>(src, Pv, ws + OFF_GV, ws + OFF_QV, ws + OFF_TSV, out);
  outh_kernel<<<512, 256, 0, stream>>>(src, Ph, ws + OFF_GH, ws + OFF_QH, ws + OFF_TSH, out);
}

// Round 2
// 243.970 us; speedup vs baseline: 1.6472x; 1.6472x over previous
//
#include <hip/hip_runtime.h>

// SoftFullAttention — restructured:
//   vertical[b,c,h,w]   = sum_c' src[c',h,w] Fv[b,w][c',c] + P_v[h,w]*s1v[b,w][c] + t1v[b,w][c]
//   horizontal[b,c,h,w] = sum_c' src[c',h,w] Fh[b,h][c',c] + P_h[w,h]*s1h[b,h][c] + t1h[b,h][c]
// F/s1/t1 derive from 32x32 Gram matrices of target columns/rows (fold_kernel).
// All fp32. out channels: [0:32) horizontal, [32:64) vertical.
//
// R2: grams + outv rebuilt for coalescing.
//  - perm(c) = (c&3)*8 + (c>>2) row permutation + c-stride ≡ 4 (mod 32) makes the
//    8 c1g lane-groups of each ds_read_b128 land on 8 distinct bank-quads.
//  - vgram: 8-w blocks (32B global segments; blk&7 XCD swizzle pairs half-lines on one L2).
//  - outv: 16-w blocks -> full 64B-line stores via oLDS [h][w][33c] re-tile.

#define OFF_GH   0
#define OFF_GV   1048576
#define OFF_QH   2097152
#define OFF_TSH  2129920
#define OFF_QV   2162688
#define OFF_TSV  2195456
#define OFF_PH   2228224
#define OFF_PV   2229504

#define FMA4(A, a4, b4) \
  A = fmaf((a4).x,(b4).x, fmaf((a4).y,(b4).y, fmaf((a4).z,(b4).z, fmaf((a4).w,(b4).w,(A)))))

// ---------------- prep: per-branch folded constants (1280 floats) ----------------
// layout: [0:1024) Wc = w1^T w2 ; [1024) a ; [1056) d ; [1088) u ; [1120) v ; [1152) alpha,beta,gamma,delta
__global__ __launch_bounds__(256) void prep_kernel(
    const float* __restrict__ w1, const float* __restrict__ b1,
    const float* __restrict__ w2, const float* __restrict__ b2,
    float* __restrict__ outp)
{
  __shared__ float lw1[1024], lw2[1024], lb1[32], lb2[32], lr1[32], lr2[32];
  const int t = threadIdx.x;
  for (int k = 0; k < 4; ++k) { lw1[t + 256*k] = w1[t + 256*k]; lw2[t + 256*k] = w2[t + 256*k]; }
  if (t < 32) { lb1[t] = b1[t]; lb2[t] = b2[t]; }
  __syncthreads();
  if (t < 32)      { float s = 0; for (int c = 0; c < 32; ++c) s += lw1[t*32 + c];      lr1[t] = s; }
  else if (t < 64) { int i = t - 32; float s = 0; for (int c = 0; c < 32; ++c) s += lw2[i*32 + c]; lr2[i] = s; }
  __syncthreads();
  for (int k = 0; k < 4; ++k) {
    const int e = t + 256*k, cp = e >> 5, cq = e & 31;
    float s = 0;
    for (int c1 = 0; c1 < 32; ++c1) s += lw1[c1*32 + cp] * lw2[c1*32 + cq];
    outp[e] = s;
  }
  if (t < 32)       { float s = 0; for (int c1 = 0; c1 < 32; ++c1) s += lw1[c1*32 + t]*lr2[c1];        outp[1024 + t] = s; }
  else if (t < 64)  { int i = t-32; float s = 0; for (int c1 = 0; c1 < 32; ++c1) s += lw1[c1*32+i]*lb2[c1]; outp[1056 + i] = s; }
  else if (t < 96)  { int i = t-64; float s = 0; for (int c1 = 0; c1 < 32; ++c1) s += lr1[c1]*lw2[c1*32+i]; outp[1088 + i] = s; }
  else if (t < 128) { int i = t-96; float s = 0; for (int c1 = 0; c1 < 32; ++c1) s += lb1[c1]*lw2[c1*32+i]; outp[1120 + i] = s; }
  else if (t == 128){ float s = 0; for (int i = 0; i < 32; ++i) s += lr1[i]*lr2[i]; outp[1152] = s; }
  else if (t == 129){ float s = 0; for (int i = 0; i < 32; ++i) s += lr1[i]*lb2[i]; outp[1153] = s; }
  else if (t == 130){ float s = 0; for (int i = 0; i < 32; ++i) s += lb1[i]*lr2[i]; outp[1154] = s; }
  else if (t == 131){ float s = 0; for (int i = 0; i < 32; ++i) s += lb1[i]*lb2[i]; outp[1155] = s; }
}

// ---------------- horizontal gram: rows of T (K along w, contiguous) ----------------
// grid 256 x 256thr. wave = one row x (b = x>>8, h = x&255). Wave-private tile [32 pc][68].
__global__ __launch_bounds__(256) void hgram_kernel(
    const float* __restrict__ T, const float* __restrict__ Ph,
    float* __restrict__ Gws, float* __restrict__ qws, float* __restrict__ tsws)
{
  __shared__ float tile[4][32*68];
  __shared__ float ptile[4][64];
  const int t = threadIdx.x, wave = t >> 6, lane = t & 63;
  const int x = blockIdx.x*4 + wave;
  const int b = x >> 8, r = x & 255;
  const int c1g = lane & 7, c2g = lane >> 3;
  const float* Trow = T + (b*32)*65536 + r*256;
  float* tw = tile[wave];
  float acc[4][4] = {};
  float qa[4] = {}, tsa[4] = {};
  const int l4 = lane >> 4, k16 = lane & 15;

  for (int ch = 0; ch < 4; ++ch) {
    const int k0 = ch*64;
    // stage 32c x 64k (coalesced 256B per 4-c group); perm(c) = (c&3)*8 + (c>>2)
    #pragma unroll
    for (int cc = 0; cc < 8; ++cc) {
      const int c = cc*4 + l4;
      const float4 v = *(const float4*)&Trow[c*65536 + k0 + k16*4];
      *(float4*)&tw[(l4*8 + cc)*68 + k16*4] = v;
    }
    ptile[wave][lane] = Ph[(k0 + lane)*256 + r];   // P(v) = Ph[v][h]
    __syncthreads();
    #pragma unroll
    for (int g4 = 0; g4 < 16; ++g4) {
      float4 av[4], bv[4];
      const float4 p4 = *(const float4*)&ptile[wave][g4*4];
      #pragma unroll
      for (int i = 0; i < 4; ++i) av[i] = *(const float4*)&tw[(8*i + c1g)*68 + g4*4];
      #pragma unroll
      for (int j = 0; j < 4; ++j) bv[j] = *(const float4*)&tw[(8*j + c2g)*68 + g4*4];
      #pragma unroll
      for (int i = 0; i < 4; ++i)
        #pragma unroll
        for (int j = 0; j < 4; ++j) FMA4(acc[i][j], av[i], bv[j]);
      #pragma unroll
      for (int j = 0; j < 4; ++j) {
        FMA4(qa[j], p4, bv[j]);
        tsa[j] += (bv[j].x + bv[j].y) + (bv[j].z + bv[j].w);
      }
    }
    __syncthreads();
  }
  const int gb = x*1024;
  #pragma unroll
  for (int i = 0; i < 4; ++i) {
    float4 o; o.x = acc[i][0]; o.y = acc[i][1]; o.z = acc[i][2]; o.w = acc[i][3];
    *(float4*)&Gws[gb + (4*c1g + i)*32 + 4*c2g] = o;
  }
  if (c1g == 0) {
    float4 q4o; q4o.x = qa[0]; q4o.y = qa[1]; q4o.z = qa[2]; q4o.w = qa[3];
    float4 t4o; t4o.x = tsa[0]; t4o.y = tsa[1]; t4o.z = tsa[2]; t4o.w = tsa[3];
    *(float4*)&qws[x*32 + 4*c2g]  = q4o;
    *(float4*)&tsws[x*32 + 4*c2g] = t4o;
  }
}

// ---------------- vertical gram: columns of T ----------------
// grid 128 x 256thr. block = (b, 8-w group), full K=256 in 8 chunks of 32 g.
// tile [32 pc][8 w][36] + 4 c-pad => stride_c = 292 (≡4 mod 32 -> conflict-free reads).
// blk&7 = XCD: adjacent w8-groups share an L2 so half-lines merge.
__global__ __launch_bounds__(256) void vgram_kernel(
    const float* __restrict__ T, const float* __restrict__ Pv,
    float* __restrict__ Gws, float* __restrict__ qws, float* __restrict__ tsws)
{
  __shared__ float tile[32*292];
  __shared__ float ptile[4][2][36];
  const int blk = blockIdx.x;
  const int xcd = blk & 7, s = blk >> 3;      // s 0..15
  const int b = s >> 2, w8l = s & 3;
  const int w0 = (xcd*4 + w8l)*8;
  const int t = threadIdx.x, wave = t >> 6, lane = t & 63;
  const int c1g = lane & 7, c2g = lane >> 3;
  const int lwb = wave*2;
  float acc[2][4][4] = {};
  float qa[2][4] = {}, tsa[2][4] = {};

  for (int chk = 0; chk < 8; ++chk) {
    const int g0 = chk*32;
    __syncthreads();
    // stage 32c x 32g x 8w (32B global segments), scatter into [pc][w][g]
    #pragma unroll
    for (int p = 0; p < 8; ++p) {
      const int rowid = p*128 + (t >> 1);
      const int c = rowid >> 5, g = rowid & 31, j = t & 1;
      const float4 v = *(const float4*)&T[((b*32 + c)*256 + g0 + g)*256 + w0 + 4*j];
      float* d = &tile[((c&3)*8 + (c>>2))*292 + g];
      d[(4*j+0)*36] = v.x; d[(4*j+1)*36] = v.y; d[(4*j+2)*36] = v.z; d[(4*j+3)*36] = v.w;
    }
    // P columns for this wave's 2 w
    if (lane < 32) ptile[wave][0][lane]    = Pv[(g0 + lane)*256      + w0 + lwb + 0];
    else           ptile[wave][1][lane-32] = Pv[(g0 + lane - 32)*256 + w0 + lwb + 1];
    __syncthreads();
    #pragma unroll
    for (int g4 = 0; g4 < 8; ++g4) {
      #pragma unroll
      for (int lw = 0; lw < 2; ++lw) {
        const int wo = (lwb + lw)*36 + g4*4;
        float4 av[4], bv[4];
        #pragma unroll
        for (int i = 0; i < 4; ++i) av[i] = *(const float4*)&tile[(8*i + c1g)*292 + wo];
        #pragma unroll
        for (int j = 0; j < 4; ++j) bv[j] = *(const float4*)&tile[(8*j + c2g)*292 + wo];
        const float4 p4 = *(const float4*)&ptile[wave][lw][g4*4];
        #pragma unroll
        for (int i = 0; i < 4; ++i)
          #pragma unroll
          for (int j = 0; j < 4; ++j) FMA4(acc[lw][i][j], av[i], bv[j]);
        #pragma unroll
        for (int j = 0; j < 4; ++j) {
          FMA4(qa[lw][j], p4, bv[j]);
          tsa[lw][j] += (bv[j].x + bv[j].y) + (bv[j].z + bv[j].w);
        }
      }
    }
  }
  #pragma unroll
  for (int lw = 0; lw < 2; ++lw) {
    const int w = w0 + lwb + lw;
    const int gb = ((b << 8) + w)*1024;
    #pragma unroll
    for (int i = 0; i < 4; ++i) {
      float4 o; o.x = acc[lw][i][0]; o.y = acc[lw][i][1]; o.z = acc[lw][i][2]; o.w = acc[lw][i][3];
      *(float4*)&Gws[gb + (4*c1g + i)*32 + 4*c2g] = o;
    }
    if (c1g == 0) {
      float4 q4o; q4o.x = qa[lw][0]; q4o.y = qa[lw][1]; q4o.z = qa[lw][2]; q4o.w = qa[lw][3];
      float4 t4o; t4o.x = tsa[lw][0]; t4o.y = tsa[lw][1]; t4o.z = tsa[lw][2]; t4o.w = tsa[lw][3];
      *(float4*)&qws[((b << 8) + w)*32 + 4*c2g]  = q4o;
      *(float4*)&tsws[((b << 8) + w)*32 + 4*c2g] = t4o;
    }
  }
}

// ---------------- fold: G,q,ts -> F (in place over G), s1,t1 (over q,ts) ----------------
__global__ __launch_bounds__(256) void fold_kernel(float* __restrict__ ws)
{
  const int wgid = blockIdx.x*4 + (threadIdx.x >> 6);  // 0..2047
  const int lane = threadIdx.x & 63;
  const int n = lane & 31, mg = lane >> 5;
  const bool horiz = (wgid < 1024);
  const int idx = wgid & 1023;
  float* G   = ws + (horiz ? OFF_GH  : OFF_GV)  + idx*1024;
  float* q   = ws + (horiz ? OFF_QH  : OFF_QV)  + idx*32;
  float* tsp = ws + (horiz ? OFF_TSH : OFF_TSV) + idx*32;
  const float* pp = ws + (horiz ? OFF_PH : OFF_PV);
  float facc[16] = {};
  float s1a = 0.f, t1a = 0.f;
  #pragma unroll
  for (int k4 = 0; k4 < 8; ++k4) {
    float g[4];
    #pragma unroll
    for (int e = 0; e < 4; ++e) g[e] = G[(k4*4 + e)*32 + n];
    const float4 u4 = *(const float4*)&pp[1088 + k4*4];
    const float4 v4 = *(const float4*)&pp[1120 + k4*4];
    s1a += u4.x*g[0] + u4.y*g[1] + u4.z*g[2] + u4.w*g[3];
    t1a += v4.x*g[0] + v4.y*g[1] + v4.z*g[2] + v4.w*g[3];
    #pragma unroll
    for (int i = 0; i < 16; ++i) {
      const float4 wc = *(const float4*)&pp[(mg*16 + i)*32 + k4*4];
      facc[i] += wc.x*g[0] + wc.y*g[1] + wc.z*g[2] + wc.w*g[3];
    }
  }
  const float qv = q[n], tv = tsp[n];
  const float al = pp[1152], be = pp[1153], ga = pp[1154], de = pp[1155];
  #pragma unroll
  for (int i = 0; i < 16; ++i) {
    const int m = mg*16 + i;
    G[m*32 + n] = facc[i] + pp[1024 + m]*qv + pp[1056 + m]*tv;   // F[m][n]
  }
  if (mg == 0) {
    q[n]   = s1a + al*qv + be*tv;   // s1
    tsp[n] = t1a + ga*qv + de*tv;   // t1
  }
}

// ---------------- vertical output ----------------
// grid 256 x 256thr: (b, 16-w group, 64-h quarter). 4 h-chunks of 16.
// S tile [32 c'][16 w][20 h] (+4 c-pad => stride 324). F/s1/t1 in regs per lane.
// oLDS [16h][16w][33c] re-tile -> full 64B-line stores.
__global__ __launch_bounds__(256) void outv_kernel(
    const float* __restrict__ S, const float* __restrict__ Pv,
    const float* __restrict__ Fws, const float* __restrict__ s1ws, const float* __restrict__ t1ws,
    float* __restrict__ out)
{
  __shared__ float tile[32*324];
  __shared__ float oLDS[16*16*33];
  __shared__ float ptile[16*16];
  const int blk = blockIdx.x;
  const int b = blk & 3;
  const int w16 = (blk >> 2) & 15;
  const int hq = blk >> 6;               // 0..3
  const int w0 = w16*16;
  const int t = threadIdx.x, wave = t >> 6, lane = t & 63;
  const int wsel = lane & 3, cg = lane >> 2;   // cg 0..15 (c-pair), wsel 0..3
  const int wloc = wave*4 + wsel;
  const int w = w0 + wloc;
  const int fb = ((b << 8) + w);
  float f[2][32];
  #pragma unroll
  for (int c = 0; c < 32; ++c) {
    f[0][c] = Fws[fb*1024 + c*32 + 2*cg + 0];
    f[1][c] = Fws[fb*1024 + c*32 + 2*cg + 1];
  }
  float s1r[2], t1r[2];
  s1r[0] = s1ws[fb*32 + 2*cg];     s1r[1] = s1ws[fb*32 + 2*cg + 1];
  t1r[0] = t1ws[fb*32 + 2*cg];     t1r[1] = t1ws[fb*32 + 2*cg + 1];

  for (int chk = 0; chk < 4; ++chk) {
    const int h0g = hq*64 + chk*16;
    __syncthreads();
    // stage S[32c'][16h][16w] -> tile[c'][w][h]
    #pragma unroll
    for (int p = 0; p < 8; ++p) {
      const int slot = p*256 + t;
      const int row = slot >> 2, j = slot & 3;
      const int cp = row >> 4, hl = row & 15;
      const float4 v = *(const float4*)&S[((b*32 + cp)*256 + h0g + hl)*256 + w0 + 4*j];
      float* d = &tile[cp*324 + hl];
      d[(4*j+0)*20] = v.x; d[(4*j+1)*20] = v.y; d[(4*j+2)*20] = v.z; d[(4*j+3)*20] = v.w;
    }
    if (t < 64) {
      const int hl = t >> 2, j = t & 3;
      const float4 v = *(const float4*)&Pv[(h0g + hl)*256 + w0 + 4*j];
      ptile[hl*16 + 4*j + 0] = v.x; ptile[hl*16 + 4*j + 1] = v.y;
      ptile[hl*16 + 4*j + 2] = v.z; ptile[hl*16 + 4*j + 3] = v.w;
    }
    __syncthreads();
    float acc[2][16] = {};
    #pragma unroll
    for (int c = 0; c < 32; ++c) {
      const float* rp = &tile[c*324 + wloc*20];
      const float4 s0 = *(const float4*)&rp[0];
      const float4 s1_ = *(const float4*)&rp[4];
      const float4 s2 = *(const float4*)&rp[8];
      const float4 s3 = *(const float4*)&rp[12];
      #pragma unroll
      for (int p = 0; p < 2; ++p) {
        const float fc = f[p][c];
        acc[p][0]  = fmaf(fc, s0.x, acc[p][0]);  acc[p][1]  = fmaf(fc, s0.y, acc[p][1]);
        acc[p][2]  = fmaf(fc, s0.z, acc[p][2]);  acc[p][3]  = fmaf(fc, s0.w, acc[p][3]);
        acc[p][4]  = fmaf(fc, s1_.x, acc[p][4]); acc[p][5]  = fmaf(fc, s1_.y, acc[p][5]);
        acc[p][6]  = fmaf(fc, s1_.z, acc[p][6]); acc[p][7]  = fmaf(fc, s1_.w, acc[p][7]);
        acc[p][8]  = fmaf(fc, s2.x, acc[p][8]);  acc[p][9]  = fmaf(fc, s2.y, acc[p][9]);
        acc[p][10] = fmaf(fc, s2.z, acc[p][10]); acc[p][11] = fmaf(fc, s2.w, acc[p][11]);
        acc[p][12] = fmaf(fc, s3.x, acc[p][12]); acc[p][13] = fmaf(fc, s3.y, acc[p][13]);
        acc[p][14] = fmaf(fc, s3.z, acc[p][14]); acc[p][15] = fmaf(fc, s3.w, acc[p][15]);
      }
    }
    #pragma unroll
    for (int e = 0; e < 16; ++e) {
      const float pv = ptile[e*16 + wloc];
      oLDS[(e*16 + wloc)*33 + 2*cg + 0] = fmaf(pv, s1r[0], acc[0][e] + t1r[0]);
      oLDS[(e*16 + wloc)*33 + 2*cg + 1] = fmaf(pv, s1r[1], acc[1][e] + t1r[1]);
    }
    __syncthreads();
    // write out: full 64B lines, 4 lanes per (c,h) row
    #pragma unroll
    for (int p = 0; p < 8; ++p) {
      const int row = p*64 + (t >> 2);
      const int c = row & 31, hl = row >> 5;
      const int wq = t & 3;
      float4 o;
      o.x = oLDS[(hl*16 + wq*4 + 0)*33 + c];
      o.y = oLDS[(hl*16 + wq*4 + 1)*33 + c];
      o.z = oLDS[(hl*16 + wq*4 + 2)*33 + c];
      o.w = oLDS[(hl*16 + wq*4 + 3)*33 + c];
      *(float4*)&out[((b*64 + 32 + c)*256 + h0g + hl)*256 + w0 + wq*4] = o;
    }
  }
}

// ---------------- horizontal output ----------------
// grid 512 (b, h-quad, w-half), wave = one h; everything w-contiguous.
__global__ __launch_bounds__(256) void outh_kernel(
    const float* __restrict__ S, const float* __restrict__ Ph,
    const float* __restrict__ Fws, const float* __restrict__ s1ws, const float* __restrict__ t1ws,
    float* __restrict__ out)
{
  __shared__ float tile[4*1156];    // [h][32 c'][32 w + 4]
  __shared__ float ptile[4*36];
  const int blk = blockIdx.x;
  const int b = blk & 3;
  const int hq = (blk >> 2) & 63;
  const int whalf = blk >> 8;
  const int h0 = hq*4;
  const int t = threadIdx.x;
  const int wave = t >> 6, lane = t & 63;
  const int cg = lane & 15, wg = lane >> 4;
  const int h = h0 + wave;
  const int base = (b << 8) + h;
  float f[2][32];
  #pragma unroll
  for (int p = 0; p < 2; ++p)
    #pragma unroll
    for (int c = 0; c < 32; ++c)
      f[p][c] = Fws[base*1024 + c*32 + 2*cg + p];
  float s1r[2], t1r[2];
  #pragma unroll
  for (int p = 0; p < 2; ++p) { s1r[p] = s1ws[base*32 + 2*cg + p]; t1r[p] = t1ws[base*32 + 2*cg + p]; }

  for (int wc = 0; wc < 4; ++wc) {
    const int w0 = (whalf*4 + wc) * 32;
    __syncthreads();
    {
      const int wq8 = t & 7, hh = (t >> 3) & 3, cq = t >> 5;
      #pragma unroll
      for (int k = 0; k < 4; ++k) {
        const int c = cq*4 + k;
        const float4 v = *(const float4*)&S[(((b*32 + c)*256) + (h0 + hh))*256 + w0 + wq8*4];
        *(float4*)&tile[hh*1156 + c*36 + wq8*4] = v;
      }
      if (t < 32) {
        #pragma unroll
        for (int hh2 = 0; hh2 < 4; ++hh2)
          ptile[hh2*36 + t] = Ph[(w0 + t)*256 + h0 + hh2];   // P_h[w][h]
      }
    }
    __syncthreads();
    float acc[2][8] = {};
    const float* tw = &tile[wave*1156];
    #pragma unroll
    for (int c = 0; c < 32; ++c) {
      const float4 lo = *(const float4*)&tw[c*36 + wg*8];
      const float4 hi = *(const float4*)&tw[c*36 + wg*8 + 4];
      #pragma unroll
      for (int p = 0; p < 2; ++p) {
        acc[p][0] += f[p][c]*lo.x; acc[p][1] += f[p][c]*lo.y;
        acc[p][2] += f[p][c]*lo.z; acc[p][3] += f[p][c]*lo.w;
        acc[p][4] += f[p][c]*hi.x; acc[p][5] += f[p][c]*hi.y;
        acc[p][6] += f[p][c]*hi.z; acc[p][7] += f[p][c]*hi.w;
      }
    }
    #pragma unroll
    for (int p = 0; p < 2; ++p) {
      float4 o1, o2;
      o1.x = acc[p][0] + ptile[wave*36 + wg*8 + 0]*s1r[p] + t1r[p];
      o1.y = acc[p][1] + ptile[wave*36 + wg*8 + 1]*s1r[p] + t1r[p];
      o1.z = acc[p][2] + ptile[wave*36 + wg*8 + 2]*s1r[p] + t1r[p];
      o1.w = acc[p][3] + ptile[wave*36 + wg*8 + 3]*s1r[p] + t1r[p];
      o2.x = acc[p][4] + ptile[wave*36 + wg*8 + 4]*s1r[p] + t1r[p];
      o2.y = acc[p][5] + ptile[wave*36 + wg*8 + 5]*s1r[p] + t1r[p];
      o2.z = acc[p][6] + ptile[wave*36 + wg*8 + 6]*s1r[p] + t1r[p];
      o2.w = acc[p][7] + ptile[wave*36 + wg*8 + 7]*s1r[p] + t1r[p];
      const int ob = (((b*64 + 2*cg + p)*256) + h)*256 + w0 + wg*8;
      *(float4*)&out[ob]     = o1;
      *(float4*)&out[ob + 4] = o2;
    }
  }
}

extern "C" void kernel_launch(void* const* d_in, const int* in_sizes, int n_in,
                              void* d_out, int out_size, void* d_ws, size_t ws_size,
                              hipStream_t stream) {
  const float* src = (const float*)d_in[0];
  const float* tgt = (const float*)d_in[1];
  const float* Pv  = (const float*)d_in[2];
  const float* Ph  = (const float*)d_in[3];
  const float* w1v = (const float*)d_in[4];
  const float* b1v = (const float*)d_in[5];
  const float* w2v = (const float*)d_in[6];
  const float* b2v = (const float*)d_in[7];
  const float* w1h = (const float*)d_in[8];
  const float* b1h = (const float*)d_in[9];
  const float* w2h = (const float*)d_in[10];
  const float* b2h = (const float*)d_in[11];
  float* ws  = (float*)d_ws;
  float* out = (float*)d_out;

  prep_kernel<<<1, 256, 0, stream>>>(w1h, b1h, w2h, b2h, ws + OFF_PH);
  prep_kernel<<<1, 256, 0, stream>>>(w1v, b1v, w2v, b2v, ws + OFF_PV);
  vgram_kernel<<<128, 256, 0, stream>>>(tgt, Pv, ws + OFF_GV, ws + OFF_QV, ws + OFF_TSV);
  hgram_kernel<<<256, 256, 0, stream>>>(tgt, Ph, ws + OFF_GH, ws + OFF_QH, ws + OFF_TSH);
  fold_kernel<<<512, 256, 0, stream>>>(ws);
  outv_kernel<<<256, 256, 0, stream>>>(src, Pv, ws + OFF_GV, ws + OFF_QV, ws + OFF_TSV, out);
  outh_kernel<<<512, 256, 0, stream>>>(src, Ph, ws + OFF_GH, ws + OFF_QH, ws + OFF_TSH, out);
}